// Round 1
// baseline (1029.048 us; speedup 1.0000x reference)
//
#include <hip/hip_runtime.h>
#include <hip/hip_bf16.h>

#define BSZ 4
#define TGT 512
#define KVL 4096
#define DM  2048
#define NH  16
#define HD  128
#define QSCALE 0.08838834764831845f  // 1/sqrt(128)

typedef __bf16 bf16_t;
typedef __bf16 bf16x4 __attribute__((ext_vector_type(4)));
typedef __bf16 bf16x8 __attribute__((ext_vector_type(8)));
typedef float  f32x4  __attribute__((ext_vector_type(4)));

#define MFMA16(a,b,c) __builtin_amdgcn_mfma_f32_16x16x32_bf16((a),(b),(c),0,0,0)

// ---------------------------------------------------------------------------
// QKV projection: P = x @ W^T + bias.  A=x [2048][2048] f32, W [2048][2048] f32.
// z=0: Q -> ws bf16 (scaled). z=1/2: K/V -> f32 into last TGT rows of cache.
// 128x128 tile, BK=32, 4 waves each 64x64 (4x4 MFMA 16x16x32 frags).
// ---------------------------------------------------------------------------
#define BM 128
#define BN 128
#define BK 32
#define LDK 40   // BK+8 pad: pitch 80B = 5*16 (b128-aligned rows)

__global__ __launch_bounds__(256, 2)
void proj_qkv(const float* __restrict__ x,
              const float* __restrict__ wq, const float* __restrict__ bq,
              const float* __restrict__ wk, const float* __restrict__ bk,
              const float* __restrict__ wv, const float* __restrict__ bv,
              bf16_t* __restrict__ qb, float* __restrict__ outk, float* __restrict__ outv)
{
  const int z = blockIdx.z;
  const float* W    = (z==0)? wq : (z==1)? wk : wv;
  const float* bias = (z==0)? bq : (z==1)? bk : bv;
  const int m0 = blockIdx.y * BM, n0 = blockIdx.x * BN;
  const int tid  = threadIdx.x;
  const int lane = tid & 63, w = tid >> 6;
  const int fm = lane & 15, kg = lane >> 4;      // frag row/col, k-group
  const int wr = (w >> 1) * 64, wc = (w & 1) * 64;
  const int ar = tid >> 3, ac = tid & 7;         // staging row / col4

  __shared__ __align__(16) bf16_t As[BM][LDK];
  __shared__ __align__(16) bf16_t Bs[BN][LDK];

  f32x4 acc[4][4];
  for (int i=0;i<4;i++) for (int j=0;j<4;j++) for (int r=0;r<4;r++) acc[i][j][r]=0.f;

  for (int k0 = 0; k0 < DM; k0 += BK) {
    #pragma unroll
    for (int p = 0; p < 4; ++p) {
      int row = ar + p*32;
      f32x4 a4f = *reinterpret_cast<const f32x4*>(&x[(size_t)(m0+row)*DM + k0 + ac*4]);
      f32x4 b4f = *reinterpret_cast<const f32x4*>(&W[(size_t)(n0+row)*DM + k0 + ac*4]);
      bf16x4 a4, b4;
      #pragma unroll
      for (int r=0;r<4;r++){ a4[r]=(bf16_t)a4f[r]; b4[r]=(bf16_t)b4f[r]; }
      *reinterpret_cast<bf16x4*>(&As[row][ac*4]) = a4;
      *reinterpret_cast<bf16x4*>(&Bs[row][ac*4]) = b4;
    }
    __syncthreads();
    bf16x8 af[4], bfr[4];
    #pragma unroll
    for (int i=0;i<4;i++){
      af[i]  = *reinterpret_cast<const bf16x8*>(&As[wr+i*16+fm][kg*8]);
      bfr[i] = *reinterpret_cast<const bf16x8*>(&Bs[wc+i*16+fm][kg*8]);
    }
    #pragma unroll
    for (int i=0;i<4;i++)
      #pragma unroll
      for (int j=0;j<4;j++)
        acc[i][j] = MFMA16(af[i], bfr[j], acc[i][j]);
    __syncthreads();
  }

  float bcol[4];
  #pragma unroll
  for (int j=0;j<4;j++) bcol[j] = bias[n0+wc+j*16+fm];
  #pragma unroll
  for (int i=0;i<4;i++)
    #pragma unroll
    for (int j=0;j<4;j++){
      const int n = n0+wc+j*16+fm;
      #pragma unroll
      for (int r=0;r<4;r++){
        const int m = m0+wr+i*16+kg*4+r;         // C/D: row=(lane>>4)*4+reg
        float v = acc[i][j][r] + bcol[j];
        if (z == 0) {
          qb[(size_t)m*DM + n] = (bf16_t)(v * QSCALE);
        } else {
          float* dst = (z==1)? outk : outv;
          const int bb = m >> 9, t = m & 511;
          dst[((size_t)bb*KVL + (KVL-TGT) + t)*DM + n] = v;
        }
      }
    }
}

// ---------------------------------------------------------------------------
// Output projection: out = attn(bf16) @ wo^T + bo  -> f32
// ---------------------------------------------------------------------------
__global__ __launch_bounds__(256, 2)
void out_proj(const bf16_t* __restrict__ attn, const float* __restrict__ wo,
              const float* __restrict__ bo, float* __restrict__ out)
{
  const int m0 = blockIdx.y * BM, n0 = blockIdx.x * BN;
  const int tid  = threadIdx.x;
  const int lane = tid & 63, w = tid >> 6;
  const int fm = lane & 15, kg = lane >> 4;
  const int wr = (w >> 1) * 64, wc = (w & 1) * 64;
  const int ar = tid >> 3, ac = tid & 7;

  __shared__ __align__(16) bf16_t As[BM][LDK];
  __shared__ __align__(16) bf16_t Bs[BN][LDK];

  f32x4 acc[4][4];
  for (int i=0;i<4;i++) for (int j=0;j<4;j++) for (int r=0;r<4;r++) acc[i][j][r]=0.f;

  for (int k0 = 0; k0 < DM; k0 += BK) {
    #pragma unroll
    for (int p = 0; p < 2; ++p) {               // A already bf16: 16B chunk copy
      int c = tid + p*256;
      int row = c >> 2, c8 = c & 3;
      *reinterpret_cast<bf16x8*>(&As[row][c8*8]) =
        *reinterpret_cast<const bf16x8*>(&attn[(size_t)(m0+row)*DM + k0 + c8*8]);
    }
    #pragma unroll
    for (int p = 0; p < 4; ++p) {               // W f32 -> bf16
      int row = ar + p*32;
      f32x4 b4f = *reinterpret_cast<const f32x4*>(&wo[(size_t)(n0+row)*DM + k0 + ac*4]);
      bf16x4 b4;
      #pragma unroll
      for (int r=0;r<4;r++) b4[r]=(bf16_t)b4f[r];
      *reinterpret_cast<bf16x4*>(&Bs[row][ac*4]) = b4;
    }
    __syncthreads();
    bf16x8 af[4], bfr[4];
    #pragma unroll
    for (int i=0;i<4;i++){
      af[i]  = *reinterpret_cast<const bf16x8*>(&As[wr+i*16+fm][kg*8]);
      bfr[i] = *reinterpret_cast<const bf16x8*>(&Bs[wc+i*16+fm][kg*8]);
    }
    #pragma unroll
    for (int i=0;i<4;i++)
      #pragma unroll
      for (int j=0;j<4;j++)
        acc[i][j] = MFMA16(af[i], bfr[j], acc[i][j]);
    __syncthreads();
  }

  float bcol[4];
  #pragma unroll
  for (int j=0;j<4;j++) bcol[j] = bo[n0+wc+j*16+fm];
  #pragma unroll
  for (int i=0;i<4;i++)
    #pragma unroll
    for (int j=0;j<4;j++){
      const int n = n0+wc+j*16+fm;
      #pragma unroll
      for (int r=0;r<4;r++){
        const int m = m0+wr+i*16+kg*4+r;
        out[(size_t)m*DM + n] = acc[i][j][r] + bcol[j];
      }
    }
}

// ---------------------------------------------------------------------------
// Flash attention: one wg per (b,h,qtile=128). 4 waves x 32 q-rows.
// KV chunk 64. K staged [kv][d] bf16; V staged transposed [d][kv] bf16 so the
// PV B-fragment is a contiguous ds_read_b128. P round-trips LDS (A-layout).
// Online softmax state (m,l) in registers, replicated per 16-lane group.
// ---------------------------------------------------------------------------
#define CHUNK 64
#define LKD 136   // HD+8   : pitch 272B = 17*16
#define LVD 72    // CHUNK+8: pitch 144B = 9*16
#define LPD 72

__global__ __launch_bounds__(256, 1)
void attn_kernel(const bf16_t* __restrict__ qb,
                 const float* __restrict__ kc,   // merged K cache (d_out region)
                 const float* __restrict__ vc,   // merged V cache
                 const float* __restrict__ mask, // [TGT][KVL]
                 bf16_t* __restrict__ attn)      // [BSZ*TGT][DM]
{
  const int qt = blockIdx.x;   // 0..3
  const int h  = blockIdx.y;   // 0..15
  const int b  = blockIdx.z;   // 0..3
  const int tid  = threadIdx.x;
  const int lane = tid & 63, w = tid >> 6;
  const int fm = lane & 15, kg = lane >> 4;
  const int sr = tid >> 5, sc = tid & 31;        // staging: row, col4

  __shared__ __align__(16) bf16_t Ks[CHUNK][LKD];
  __shared__ __align__(16) bf16_t Vt[HD][LVD];
  __shared__ __align__(16) bf16_t Ps[4][32][LPD];

  const int qbase = b*TGT + qt*128 + w*32;       // global row in [0,2048)

  // Q fragments (A-layout: m=lane&15, k=kg*8+j), already scaled bf16
  bf16x8 qf[2][4];
  #pragma unroll
  for (int mi=0;mi<2;mi++)
    #pragma unroll
    for (int kk=0;kk<4;kk++)
      qf[mi][kk] = *reinterpret_cast<const bf16x8*>(
          &qb[(size_t)(qbase + mi*16 + fm)*DM + h*HD + kk*32 + kg*8]);

  f32x4 o[2][8];
  #pragma unroll
  for (int mi=0;mi<2;mi++) for (int nt=0;nt<8;nt++) for (int r=0;r<4;r++) o[mi][nt][r]=0.f;
  float mst[2][4], lst[2][4];
  #pragma unroll
  for (int mi=0;mi<2;mi++) for (int r=0;r<4;r++){ mst[mi][r]=-1e30f; lst[mi][r]=0.f; }

  const float* kbase = kc + (size_t)b*KVL*DM + h*HD;
  const float* vbase = vc + (size_t)b*KVL*DM + h*HD;

  for (int kv0 = 0; kv0 < KVL; kv0 += CHUNK) {
    // ---- stage K (row-major) and V (transposed), f32 -> bf16 ----
    #pragma unroll
    for (int p = 0; p < 8; ++p) {
      int row = sr + p*8;
      f32x4 kv4 = *reinterpret_cast<const f32x4*>(&kbase[(size_t)(kv0+row)*DM + sc*4]);
      f32x4 vv4 = *reinterpret_cast<const f32x4*>(&vbase[(size_t)(kv0+row)*DM + sc*4]);
      bf16x4 k4;
      #pragma unroll
      for (int jj=0;jj<4;jj++) k4[jj]=(bf16_t)kv4[jj];
      *reinterpret_cast<bf16x4*>(&Ks[row][sc*4]) = k4;
      #pragma unroll
      for (int jj=0;jj<4;jj++) Vt[sc*4+jj][row] = (bf16_t)vv4[jj];
    }
    __syncthreads();

    // ---- S = Q K^T  (16x16 tiles over 64 kv cols, K-dim = HD=128) ----
    f32x4 s[2][4];
    #pragma unroll
    for (int mi=0;mi<2;mi++) for (int nt=0;nt<4;nt++) for (int r=0;r<4;r++) s[mi][nt][r]=0.f;
    #pragma unroll
    for (int nt=0;nt<4;nt++){
      #pragma unroll
      for (int kk=0;kk<4;kk++){
        bf16x8 kf = *reinterpret_cast<const bf16x8*>(&Ks[nt*16+fm][kk*32+kg*8]);
        s[0][nt] = MFMA16(qf[0][kk], kf, s[0][nt]);
        s[1][nt] = MFMA16(qf[1][kk], kf, s[1][nt]);
      }
    }

    // ---- mask + online softmax (per 16-row tile mi) ----
    #pragma unroll
    for (int mi=0;mi<2;mi++){
      float pm[4][4];
      #pragma unroll
      for (int nt=0;nt<4;nt++)
        #pragma unroll
        for (int r=0;r<4;r++){
          int qrow = qt*128 + w*32 + mi*16 + kg*4 + r;   // [0,512)
          pm[nt][r] = s[mi][nt][r] + mask[(size_t)qrow*KVL + kv0 + nt*16 + fm];
        }
      float cm[4];
      #pragma unroll
      for (int r=0;r<4;r++)
        cm[r] = fmaxf(fmaxf(pm[0][r],pm[1][r]), fmaxf(pm[2][r],pm[3][r]));
      #pragma unroll
      for (int off=1; off<16; off<<=1)
        #pragma unroll
        for (int r=0;r<4;r++) cm[r] = fmaxf(cm[r], __shfl_xor(cm[r], off, 64));
      float alpha[4], rs[4];
      #pragma unroll
      for (int r=0;r<4;r++){
        float mn = fmaxf(mst[mi][r], cm[r]);
        alpha[r] = __expf(mst[mi][r] - mn);
        mst[mi][r] = mn;
        rs[r] = 0.f;
      }
      #pragma unroll
      for (int nt=0;nt<4;nt++)
        #pragma unroll
        for (int r=0;r<4;r++){
          float p = __expf(pm[nt][r] - mst[mi][r]);
          pm[nt][r] = p; rs[r] += p;
        }
      #pragma unroll
      for (int off=1; off<16; off<<=1)
        #pragma unroll
        for (int r=0;r<4;r++) rs[r] += __shfl_xor(rs[r], off, 64);
      #pragma unroll
      for (int r=0;r<4;r++) lst[mi][r] = lst[mi][r]*alpha[r] + rs[r];
      #pragma unroll
      for (int nt=0;nt<8;nt++)
        #pragma unroll
        for (int r=0;r<4;r++) o[mi][nt][r] *= alpha[r];
      // P -> LDS in A-operand layout (row-major [q][kv])
      #pragma unroll
      for (int nt=0;nt<4;nt++)
        #pragma unroll
        for (int r=0;r<4;r++)
          Ps[w][mi*16 + kg*4 + r][nt*16 + fm] = (bf16_t)pm[nt][r];
    }

    // ---- O += P V  (K-dim = chunk 64: 2 k-steps) ----
    #pragma unroll
    for (int ks=0; ks<2; ks++){
      bf16x8 pa0 = *reinterpret_cast<const bf16x8*>(&Ps[w][fm     ][ks*32+kg*8]);
      bf16x8 pa1 = *reinterpret_cast<const bf16x8*>(&Ps[w][16 + fm][ks*32+kg*8]);
      #pragma unroll
      for (int nt=0; nt<8; nt++){
        bf16x8 vf = *reinterpret_cast<const bf16x8*>(&Vt[nt*16+fm][ks*32+kg*8]);
        o[0][nt] = MFMA16(pa0, vf, o[0][nt]);
        o[1][nt] = MFMA16(pa1, vf, o[1][nt]);
      }
    }
    __syncthreads();
  }

  // ---- epilogue: attn = O / l  (bf16) ----
  #pragma unroll
  for (int mi=0;mi<2;mi++){
    float inv[4];
    #pragma unroll
    for (int r=0;r<4;r++) inv[r] = 1.0f / lst[mi][r];
    #pragma unroll
    for (int nt=0;nt<8;nt++)
      #pragma unroll
      for (int r=0;r<4;r++){
        int m = qbase + mi*16 + kg*4 + r;
        attn[(size_t)m*DM + h*HD + nt*16 + fm] = (bf16_t)(o[mi][nt][r] * inv[r]);
      }
  }
}

// ---------------------------------------------------------------------------
extern "C" void kernel_launch(void* const* d_in, const int* in_sizes, int n_in,
                              void* d_out, int out_size, void* d_ws, size_t ws_size,
                              hipStream_t stream)
{
  const float* x    = (const float*)d_in[0];
  const float* kcin = (const float*)d_in[1];
  const float* vcin = (const float*)d_in[2];
  const float* mask = (const float*)d_in[3];
  const float* wq = (const float*)d_in[4];  const float* bq = (const float*)d_in[5];
  const float* wk = (const float*)d_in[6];  const float* bk = (const float*)d_in[7];
  const float* wv = (const float*)d_in[8];  const float* bv = (const float*)d_in[9];
  const float* wo = (const float*)d_in[10]; const float* bo = (const float*)d_in[11];

  float* out  = (float*)d_out;
  float* outk = out  + (size_t)BSZ*TGT*DM;   // +4,194,304
  float* outv = outk + (size_t)BSZ*KVL*DM;   // +33,554,432

  bf16_t* qb   = (bf16_t*)d_ws;              // 8 MB: scaled Q, bf16 [2048][2048]
  bf16_t* attn = qb + (size_t)BSZ*TGT*DM;    // 8 MB: attention output, bf16

  const size_t cache_bytes = (size_t)BSZ*KVL*DM*sizeof(float);
  hipMemcpyAsync(outk, kcin, cache_bytes, hipMemcpyDeviceToDevice, stream);
  hipMemcpyAsync(outv, vcin, cache_bytes, hipMemcpyDeviceToDevice, stream);

  proj_qkv  <<<dim3(16,16,3), 256, 0, stream>>>(x, wq,bq, wk,bk, wv,bv, qb, outk, outv);
  attn_kernel<<<dim3(4,16,4), 256, 0, stream>>>(qb, outk, outv, mask, attn);
  out_proj  <<<dim3(16,16,1), 256, 0, stream>>>(attn, wo, bo, out);
}

// Round 2
// 869.245 us; speedup vs baseline: 1.1838x; 1.1838x over previous
//
#include <hip/hip_runtime.h>
#include <hip/hip_bf16.h>

#define BSZ 4
#define TGT 512
#define KVL 4096
#define DM  2048
#define NH  16
#define HD  128
#define QSCALE 0.08838834764831845f  // 1/sqrt(128)

typedef __bf16 bf16_t;
typedef __bf16 bf16x4 __attribute__((ext_vector_type(4)));
typedef __bf16 bf16x8 __attribute__((ext_vector_type(8)));
typedef float  f32x4  __attribute__((ext_vector_type(4)));

#define MFMA16(a,b,c) __builtin_amdgcn_mfma_f32_16x16x32_bf16((a),(b),(c),0,0,0)

// ---------------------------------------------------------------------------
// Copy only the preserved cache rows [0, KVL-TGT) for both caches.
// (Last TGT rows are produced by proj_qkv; copying them would be wasted BW.)
// 2 caches x 4 b x 3584 rows x 512 f32x4 = 14,680,064 f32x4.
// ---------------------------------------------------------------------------
#define OLDROWS (KVL - TGT)           // 3584
#define PERB    (OLDROWS * (DM/4))    // 1,835,008 f32x4 per batch
#define PERC    (BSZ * PERB)          // 7,340,032 per cache

__global__ __launch_bounds__(256)
void cache_copy(const float* __restrict__ kcin, const float* __restrict__ vcin,
                float* __restrict__ outk, float* __restrict__ outv)
{
  for (size_t i = (size_t)blockIdx.x*256 + threadIdx.x; i < 2ull*PERC;
       i += (size_t)gridDim.x*256) {
    const float* src; float* dst; size_t j;
    if (i < PERC) { src = kcin; dst = outk; j = i; }
    else          { src = vcin; dst = outv; j = i - PERC; }
    size_t b = j / PERB;
    size_t off = j + b * (size_t)(TGT * (DM/4));   // skip the TGT-row gap per batch
    reinterpret_cast<f32x4*>(dst)[off] = reinterpret_cast<const f32x4*>(src)[off];
  }
}

// ---------------------------------------------------------------------------
// QKV projection: P = x @ W^T + bias.
// z=0: Q -> ws bf16 (scaled). z=1/2: K/V -> f32 into last TGT rows of cache.
// ---------------------------------------------------------------------------
#define BM 128
#define BN 128
#define BK 32
#define LDK 40

__global__ __launch_bounds__(256, 2)
void proj_qkv(const float* __restrict__ x,
              const float* __restrict__ wq, const float* __restrict__ bq,
              const float* __restrict__ wk, const float* __restrict__ bk,
              const float* __restrict__ wv, const float* __restrict__ bv,
              bf16_t* __restrict__ qb, float* __restrict__ outk, float* __restrict__ outv)
{
  const int z = blockIdx.z;
  const float* W    = (z==0)? wq : (z==1)? wk : wv;
  const float* bias = (z==0)? bq : (z==1)? bk : bv;
  const int m0 = blockIdx.y * BM, n0 = blockIdx.x * BN;
  const int tid  = threadIdx.x;
  const int lane = tid & 63, w = tid >> 6;
  const int fm = lane & 15, kg = lane >> 4;
  const int wr = (w >> 1) * 64, wc = (w & 1) * 64;
  const int ar = tid >> 3, ac = tid & 7;

  __shared__ __align__(16) bf16_t As[BM][LDK];
  __shared__ __align__(16) bf16_t Bs[BN][LDK];

  f32x4 acc[4][4];
  for (int i=0;i<4;i++) for (int j=0;j<4;j++) for (int r=0;r<4;r++) acc[i][j][r]=0.f;

  for (int k0 = 0; k0 < DM; k0 += BK) {
    #pragma unroll
    for (int p = 0; p < 4; ++p) {
      int row = ar + p*32;
      f32x4 a4f = *reinterpret_cast<const f32x4*>(&x[(size_t)(m0+row)*DM + k0 + ac*4]);
      f32x4 b4f = *reinterpret_cast<const f32x4*>(&W[(size_t)(n0+row)*DM + k0 + ac*4]);
      bf16x4 a4, b4;
      #pragma unroll
      for (int r=0;r<4;r++){ a4[r]=(bf16_t)a4f[r]; b4[r]=(bf16_t)b4f[r]; }
      *reinterpret_cast<bf16x4*>(&As[row][ac*4]) = a4;
      *reinterpret_cast<bf16x4*>(&Bs[row][ac*4]) = b4;
    }
    __syncthreads();
    bf16x8 af[4], bfr[4];
    #pragma unroll
    for (int i=0;i<4;i++){
      af[i]  = *reinterpret_cast<const bf16x8*>(&As[wr+i*16+fm][kg*8]);
      bfr[i] = *reinterpret_cast<const bf16x8*>(&Bs[wc+i*16+fm][kg*8]);
    }
    #pragma unroll
    for (int i=0;i<4;i++)
      #pragma unroll
      for (int j=0;j<4;j++)
        acc[i][j] = MFMA16(af[i], bfr[j], acc[i][j]);
    __syncthreads();
  }

  float bcol[4];
  #pragma unroll
  for (int j=0;j<4;j++) bcol[j] = bias[n0+wc+j*16+fm];
  #pragma unroll
  for (int i=0;i<4;i++)
    #pragma unroll
    for (int j=0;j<4;j++){
      const int n = n0+wc+j*16+fm;
      #pragma unroll
      for (int r=0;r<4;r++){
        const int m = m0+wr+i*16+kg*4+r;
        float v = acc[i][j][r] + bcol[j];
        if (z == 0) {
          qb[(size_t)m*DM + n] = (bf16_t)(v * QSCALE);
        } else {
          float* dst = (z==1)? outk : outv;
          const int bb = m >> 9, t = m & 511;
          dst[((size_t)bb*KVL + (KVL-TGT) + t)*DM + n] = v;
        }
      }
    }
}

// ---------------------------------------------------------------------------
// Output projection: out = attn(bf16) @ wo^T + bo  -> f32
// ---------------------------------------------------------------------------
__global__ __launch_bounds__(256, 2)
void out_proj(const bf16_t* __restrict__ attn, const float* __restrict__ wo,
              const float* __restrict__ bo, float* __restrict__ out)
{
  const int m0 = blockIdx.y * BM, n0 = blockIdx.x * BN;
  const int tid  = threadIdx.x;
  const int lane = tid & 63, w = tid >> 6;
  const int fm = lane & 15, kg = lane >> 4;
  const int wr = (w >> 1) * 64, wc = (w & 1) * 64;
  const int ar = tid >> 3, ac = tid & 7;

  __shared__ __align__(16) bf16_t As[BM][LDK];
  __shared__ __align__(16) bf16_t Bs[BN][LDK];

  f32x4 acc[4][4];
  for (int i=0;i<4;i++) for (int j=0;j<4;j++) for (int r=0;r<4;r++) acc[i][j][r]=0.f;

  for (int k0 = 0; k0 < DM; k0 += BK) {
    #pragma unroll
    for (int p = 0; p < 2; ++p) {
      int c = tid + p*256;
      int row = c >> 2, c8 = c & 3;
      *reinterpret_cast<bf16x8*>(&As[row][c8*8]) =
        *reinterpret_cast<const bf16x8*>(&attn[(size_t)(m0+row)*DM + k0 + c8*8]);
    }
    #pragma unroll
    for (int p = 0; p < 4; ++p) {
      int row = ar + p*32;
      f32x4 b4f = *reinterpret_cast<const f32x4*>(&wo[(size_t)(n0+row)*DM + k0 + ac*4]);
      bf16x4 b4;
      #pragma unroll
      for (int r=0;r<4;r++) b4[r]=(bf16_t)b4f[r];
      *reinterpret_cast<bf16x4*>(&Bs[row][ac*4]) = b4;
    }
    __syncthreads();
    bf16x8 af[4], bfr[4];
    #pragma unroll
    for (int i=0;i<4;i++){
      af[i]  = *reinterpret_cast<const bf16x8*>(&As[wr+i*16+fm][kg*8]);
      bfr[i] = *reinterpret_cast<const bf16x8*>(&Bs[wc+i*16+fm][kg*8]);
    }
    #pragma unroll
    for (int i=0;i<4;i++)
      #pragma unroll
      for (int j=0;j<4;j++)
        acc[i][j] = MFMA16(af[i], bfr[j], acc[i][j]);
    __syncthreads();
  }

  float bcol[4];
  #pragma unroll
  for (int j=0;j<4;j++) bcol[j] = bo[n0+wc+j*16+fm];
  #pragma unroll
  for (int i=0;i<4;i++)
    #pragma unroll
    for (int j=0;j<4;j++){
      const int n = n0+wc+j*16+fm;
      #pragma unroll
      for (int r=0;r<4;r++){
        const int m = m0+wr+i*16+kg*4+r;
        out[(size_t)m*DM + n] = acc[i][j][r] + bcol[j];
      }
    }
}

// ---------------------------------------------------------------------------
// Flash attention with KV-split=2 (flash-decoding). Grid (qt=4, h=16, b*2+sp=8)
// = 512 blocks -> 2 blocks/CU (8 waves/CU). Each block: KV range of 2048, 32
// chunks of 64. Writes UNNORMALIZED partial O + per-row (m,l) to ws.
// V staged transposed via per-thread-d ownership: coalesced scalar global
// reads along kv, b128 LDS writes along kv -> conflict-free (8 lanes per
// 4-bank set, the b128 floor).
// ---------------------------------------------------------------------------
#define CHUNK 64
#define KVSPLIT 2
#define KVRANGE (KVL / KVSPLIT)   // 2048
#define LKD 136   // HD+8
#define LVD 72    // CHUNK+8
#define LPD 72

__global__ __launch_bounds__(256, 2)
void attn_split(const bf16_t* __restrict__ qb,
                const float* __restrict__ kc,
                const float* __restrict__ vc,
                const float* __restrict__ mask,
                float* __restrict__ Opart,   // [2*256][128*128]
                float* __restrict__ Mpart)   // [2*256][128*2]
{
  const int qt = blockIdx.x;          // 0..3
  const int h  = blockIdx.y;          // 0..15
  const int b  = blockIdx.z >> 1;     // 0..3
  const int sp = blockIdx.z & 1;      // kv split
  const int tid  = threadIdx.x;
  const int lane = tid & 63, w = tid >> 6;
  const int fm = lane & 15, kg = lane >> 4;
  const int sr = tid >> 5, sc = tid & 31;   // K staging
  const int vd = tid & 127, vh = tid >> 7;  // V staging: own one d column

  __shared__ __align__(16) bf16_t Ks[CHUNK][LKD];
  __shared__ __align__(16) bf16_t Vt[HD][LVD];
  __shared__ __align__(16) bf16_t Ps[4][32][LPD];

  const int qbase = b*TGT + qt*128 + w*32;

  bf16x8 qf[2][4];
  #pragma unroll
  for (int mi=0;mi<2;mi++)
    #pragma unroll
    for (int kk=0;kk<4;kk++)
      qf[mi][kk] = *reinterpret_cast<const bf16x8*>(
          &qb[(size_t)(qbase + mi*16 + fm)*DM + h*HD + kk*32 + kg*8]);

  f32x4 o[2][8];
  #pragma unroll
  for (int mi=0;mi<2;mi++) for (int nt=0;nt<8;nt++) for (int r=0;r<4;r++) o[mi][nt][r]=0.f;
  float mst[2][4], lst[2][4];
  #pragma unroll
  for (int mi=0;mi<2;mi++) for (int r=0;r<4;r++){ mst[mi][r]=-1e30f; lst[mi][r]=0.f; }

  const float* kbase = kc + (size_t)b*KVL*DM + h*HD;
  const float* vbase = vc + (size_t)b*KVL*DM + h*HD;
  const int kvbeg = sp * KVRANGE;

  for (int kv0 = kvbeg; kv0 < kvbeg + KVRANGE; kv0 += CHUNK) {
    // ---- stage K row-major (f32x4 coalesced, cvt, 8B LDS stores) ----
    #pragma unroll
    for (int p = 0; p < 8; ++p) {
      int row = sr + p*8;
      f32x4 kv4 = *reinterpret_cast<const f32x4*>(&kbase[(size_t)(kv0+row)*DM + sc*4]);
      bf16x4 k4;
      #pragma unroll
      for (int jj=0;jj<4;jj++) k4[jj]=(bf16_t)kv4[jj];
      *reinterpret_cast<bf16x4*>(&Ks[row][sc*4]) = k4;
    }
    // ---- stage V transposed: thread owns column d=vd, kv half vh ----
    {
      float vv[32];
      #pragma unroll
      for (int i=0;i<32;i++)
        vv[i] = vbase[(size_t)(kv0 + vh*32 + i)*DM + vd];
      #pragma unroll
      for (int i8=0;i8<4;i8++){
        bf16x8 v8;
        #pragma unroll
        for (int j=0;j<8;j++) v8[j] = (bf16_t)vv[i8*8+j];
        *reinterpret_cast<bf16x8*>(&Vt[vd][vh*32 + i8*8]) = v8;
      }
    }
    __syncthreads();

    // ---- S = Q K^T ----
    f32x4 s[2][4];
    #pragma unroll
    for (int mi=0;mi<2;mi++) for (int nt=0;nt<4;nt++) for (int r=0;r<4;r++) s[mi][nt][r]=0.f;
    #pragma unroll
    for (int nt=0;nt<4;nt++){
      #pragma unroll
      for (int kk=0;kk<4;kk++){
        bf16x8 kf = *reinterpret_cast<const bf16x8*>(&Ks[nt*16+fm][kk*32+kg*8]);
        s[0][nt] = MFMA16(qf[0][kk], kf, s[0][nt]);
        s[1][nt] = MFMA16(qf[1][kk], kf, s[1][nt]);
      }
    }

    // ---- mask + online softmax ----
    #pragma unroll
    for (int mi=0;mi<2;mi++){
      float pm[4][4];
      #pragma unroll
      for (int nt=0;nt<4;nt++)
        #pragma unroll
        for (int r=0;r<4;r++){
          int qrow = qt*128 + w*32 + mi*16 + kg*4 + r;
          pm[nt][r] = s[mi][nt][r] + mask[(size_t)qrow*KVL + kv0 + nt*16 + fm];
        }
      float cm[4];
      #pragma unroll
      for (int r=0;r<4;r++)
        cm[r] = fmaxf(fmaxf(pm[0][r],pm[1][r]), fmaxf(pm[2][r],pm[3][r]));
      #pragma unroll
      for (int off=1; off<16; off<<=1)
        #pragma unroll
        for (int r=0;r<4;r++) cm[r] = fmaxf(cm[r], __shfl_xor(cm[r], off, 64));
      float alpha[4], rs[4];
      #pragma unroll
      for (int r=0;r<4;r++){
        float mn = fmaxf(mst[mi][r], cm[r]);
        alpha[r] = __expf(mst[mi][r] - mn);
        mst[mi][r] = mn;
        rs[r] = 0.f;
      }
      #pragma unroll
      for (int nt=0;nt<4;nt++)
        #pragma unroll
        for (int r=0;r<4;r++){
          float p = __expf(pm[nt][r] - mst[mi][r]);
          pm[nt][r] = p; rs[r] += p;
        }
      #pragma unroll
      for (int off=1; off<16; off<<=1)
        #pragma unroll
        for (int r=0;r<4;r++) rs[r] += __shfl_xor(rs[r], off, 64);
      #pragma unroll
      for (int r=0;r<4;r++) lst[mi][r] = lst[mi][r]*alpha[r] + rs[r];
      #pragma unroll
      for (int nt=0;nt<8;nt++)
        #pragma unroll
        for (int r=0;r<4;r++) o[mi][nt][r] *= alpha[r];
      #pragma unroll
      for (int nt=0;nt<4;nt++)
        #pragma unroll
        for (int r=0;r<4;r++)
          Ps[w][mi*16 + kg*4 + r][nt*16 + fm] = (bf16_t)pm[nt][r];
    }

    // ---- O += P V ----
    #pragma unroll
    for (int ks=0; ks<2; ks++){
      bf16x8 pa0 = *reinterpret_cast<const bf16x8*>(&Ps[w][fm     ][ks*32+kg*8]);
      bf16x8 pa1 = *reinterpret_cast<const bf16x8*>(&Ps[w][16 + fm][ks*32+kg*8]);
      #pragma unroll
      for (int nt=0; nt<8; nt++){
        bf16x8 vf = *reinterpret_cast<const bf16x8*>(&Vt[nt*16+fm][ks*32+kg*8]);
        o[0][nt] = MFMA16(pa0, vf, o[0][nt]);
        o[1][nt] = MFMA16(pa1, vf, o[1][nt]);
      }
    }
    __syncthreads();
  }

  // ---- write unnormalized partial O + (m,l) ----
  const int pidx = (b*NH + h)*4 + qt;            // 0..255
  float* obuf = Opart + ((size_t)sp*256 + pidx)*16384;
  #pragma unroll
  for (int mi=0;mi<2;mi++)
    #pragma unroll
    for (int nt=0;nt<8;nt++)
      #pragma unroll
      for (int r=0;r<4;r++){
        int qrl = w*32 + mi*16 + kg*4 + r;
        obuf[(size_t)qrl*HD + nt*16 + fm] = o[mi][nt][r];
      }
  if (fm == 0) {
    float* mbuf = Mpart + ((size_t)sp*256 + pidx)*256;
    #pragma unroll
    for (int mi=0;mi<2;mi++)
      #pragma unroll
      for (int r=0;r<4;r++){
        int qrl = w*32 + mi*16 + kg*4 + r;
        mbuf[qrl*2 + 0] = mst[mi][r];
        mbuf[qrl*2 + 1] = lst[mi][r];
      }
  }
}

// ---------------------------------------------------------------------------
// Combine the 2 KV-split partials -> attn bf16 [2048][2048]
// ---------------------------------------------------------------------------
__global__ __launch_bounds__(256)
void attn_combine(const float* __restrict__ Opart, const float* __restrict__ Mpart,
                  bf16_t* __restrict__ attn)
{
  const int pidx = blockIdx.x;           // 0..255 = ((b*16+h)*4+qt)
  const int b  = pidx >> 6;
  const int h  = (pidx >> 2) & 15;
  const int qt = pidx & 3;
  const float* o0 = Opart + (size_t)pidx*16384;
  const float* o1 = Opart + (size_t)(256 + pidx)*16384;
  const float* m0b = Mpart + (size_t)pidx*256;
  const float* m1b = Mpart + (size_t)(256 + pidx)*256;

  for (int e = threadIdx.x; e < 4096; e += 256) {
    int qrow = e >> 5, c4 = e & 31;
    float m0 = m0b[qrow*2], l0 = m0b[qrow*2+1];
    float m1 = m1b[qrow*2], l1 = m1b[qrow*2+1];
    float mm = fmaxf(m0, m1);
    float s0 = __expf(m0 - mm), s1 = __expf(m1 - mm);
    float inv = 1.0f / (l0*s0 + l1*s1);
    f32x4 a = *reinterpret_cast<const f32x4*>(&o0[qrow*HD + c4*4]);
    f32x4 c = *reinterpret_cast<const f32x4*>(&o1[qrow*HD + c4*4]);
    bf16x4 r;
    #pragma unroll
    for (int j=0;j<4;j++) r[j] = (bf16_t)((a[j]*s0 + c[j]*s1) * inv);
    *reinterpret_cast<bf16x4*>(
        &attn[(size_t)(b*TGT + qt*128 + qrow)*DM + h*HD + c4*4]) = r;
  }
}

// ---------------------------------------------------------------------------
extern "C" void kernel_launch(void* const* d_in, const int* in_sizes, int n_in,
                              void* d_out, int out_size, void* d_ws, size_t ws_size,
                              hipStream_t stream)
{
  const float* x    = (const float*)d_in[0];
  const float* kcin = (const float*)d_in[1];
  const float* vcin = (const float*)d_in[2];
  const float* mask = (const float*)d_in[3];
  const float* wq = (const float*)d_in[4];  const float* bq = (const float*)d_in[5];
  const float* wk = (const float*)d_in[6];  const float* bk = (const float*)d_in[7];
  const float* wv = (const float*)d_in[8];  const float* bv = (const float*)d_in[9];
  const float* wo = (const float*)d_in[10]; const float* bo = (const float*)d_in[11];

  float* out  = (float*)d_out;
  float* outk = out  + (size_t)BSZ*TGT*DM;
  float* outv = outk + (size_t)BSZ*KVL*DM;

  bf16_t* qb    = (bf16_t*)d_ws;                       // 8 MB
  bf16_t* attn  = qb + (size_t)BSZ*TGT*DM;             // 8 MB
  float*  Opart = (float*)((char*)d_ws + (16ull<<20)); // 32 MB: [512][16384]
  float*  Mpart = Opart + (size_t)512*16384;           // 0.5 MB

  cache_copy <<<7168, 256, 0, stream>>>(kcin, vcin, outk, outv);
  proj_qkv   <<<dim3(16,16,3), 256, 0, stream>>>(x, wq,bq, wk,bk, wv,bv, qb, outk, outv);
  attn_split <<<dim3(4,16,8), 256, 0, stream>>>(qb, outk, outv, mask, Opart, Mpart);
  attn_combine<<<256, 256, 0, stream>>>(Opart, Mpart, attn);
  out_proj   <<<dim3(16,16,1), 256, 0, stream>>>(attn, wo, bo, out);
}